// Round 1
// baseline (117.345 us; speedup 1.0000x reference)
//
#include <hip/hip_runtime.h>
#include <hip/hip_bf16.h>

// out[b] = dot(W1[i1[b]], W2[i2[b]]) + b1[i1[b]] + b2[i2[b]]
// EMBED_DIM = 128, BATCH = 16384, VOCAB = 100000.
// 32 lanes per row; each lane holds 4 floats (float4) of each embedding.

#define EMBED_DIM 128

__global__ __launch_bounds__(256) void fused_embed_dot_kernel(
    const int* __restrict__ i1, const int* __restrict__ i2,
    const float* __restrict__ W1, const float* __restrict__ W2,
    const float* __restrict__ b1, const float* __restrict__ b2,
    float* __restrict__ out, int batch) {

    int t = blockIdx.x * blockDim.x + threadIdx.x;
    int row = t >> 5;           // 32 lanes per row
    int lane = t & 31;
    if (row >= batch) return;

    int idx1 = i1[row];
    int idx2 = i2[row];

    const float4 a = *reinterpret_cast<const float4*>(W1 + (size_t)idx1 * EMBED_DIM + lane * 4);
    const float4 b = *reinterpret_cast<const float4*>(W2 + (size_t)idx2 * EMBED_DIM + lane * 4);

    float s = a.x * b.x + a.y * b.y + a.z * b.z + a.w * b.w;

    // Reduce across the 32-lane group (xor masks <32 stay within the aligned group)
    s += __shfl_xor(s, 16);
    s += __shfl_xor(s, 8);
    s += __shfl_xor(s, 4);
    s += __shfl_xor(s, 2);
    s += __shfl_xor(s, 1);

    if (lane == 0) {
        out[row] = s + b1[idx1] + b2[idx2];
    }
}

extern "C" void kernel_launch(void* const* d_in, const int* in_sizes, int n_in,
                              void* d_out, int out_size, void* d_ws, size_t ws_size,
                              hipStream_t stream) {
    const int*   i1 = (const int*)d_in[0];
    const int*   i2 = (const int*)d_in[1];
    const float* W1 = (const float*)d_in[2];
    const float* W2 = (const float*)d_in[3];
    const float* b1 = (const float*)d_in[4];
    const float* b2 = (const float*)d_in[5];
    float* out = (float*)d_out;

    const int batch = in_sizes[0];              // 16384
    const int threads_per_row = 32;
    const int block = 256;
    const int rows_per_block = block / threads_per_row;   // 8
    const int grid = (batch + rows_per_block - 1) / rows_per_block;  // 2048

    fused_embed_dot_kernel<<<grid, block, 0, stream>>>(i1, i2, W1, W2, b1, b2, out, batch);
}

// Round 2
// 116.828 us; speedup vs baseline: 1.0044x; 1.0044x over previous
//
#include <hip/hip_runtime.h>
#include <hip/hip_bf16.h>

// out[b] = dot(W1[i1[b]], W2[i2[b]]) + b1[i1[b]] + b2[i2[b]]
// EMBED_DIM = 128, BATCH = 16384, VOCAB = 100000.
// 32 lanes per row, 2 rows per lane-group: 4 independent float4 gathers in
// flight per lane; bias gathers hoisted before the reduce (uniform-address
// loads broadcast-coalesce to one request per wave).

#define EMBED_DIM 128

__global__ __launch_bounds__(256) void fused_embed_dot_kernel(
    const int* __restrict__ i1, const int* __restrict__ i2,
    const float* __restrict__ W1, const float* __restrict__ W2,
    const float* __restrict__ b1, const float* __restrict__ b2,
    float* __restrict__ out, int batch) {

    int t = blockIdx.x * blockDim.x + threadIdx.x;
    int g = t >> 5;           // 32-lane group id
    int lane = t & 31;
    int row0 = g * 2;         // this group handles rows row0, row0+1
    if (row0 >= batch) return;

    // Index loads (group-uniform addresses)
    int ia0 = i1[row0],     ib0 = i2[row0];
    int ia1 = i1[row0 + 1], ib1 = i2[row0 + 1];

    // Issue all 4 embedding gathers + 4 bias gathers back-to-back (max MLP)
    const float4 a0 = *(reinterpret_cast<const float4*>(W1 + (size_t)ia0 * EMBED_DIM) + lane);
    const float4 v0 = *(reinterpret_cast<const float4*>(W2 + (size_t)ib0 * EMBED_DIM) + lane);
    const float4 a1 = *(reinterpret_cast<const float4*>(W1 + (size_t)ia1 * EMBED_DIM) + lane);
    const float4 v1 = *(reinterpret_cast<const float4*>(W2 + (size_t)ib1 * EMBED_DIM) + lane);
    // Uniform-address bias loads: one broadcast request per wave, overlapped
    // with the embedding-gather latency instead of serialized after the reduce.
    const float bias0 = b1[ia0] + b2[ib0];
    const float bias1 = b1[ia1] + b2[ib1];

    float s0 = a0.x * v0.x + a0.y * v0.y + a0.z * v0.z + a0.w * v0.w;
    float s1 = a1.x * v1.x + a1.y * v1.y + a1.z * v1.z + a1.w * v1.w;

    // Butterfly reduce within the 32-lane group (masks <32 stay in-group)
    #pragma unroll
    for (int m = 16; m >= 1; m >>= 1) {
        s0 += __shfl_xor(s0, m);
        s1 += __shfl_xor(s1, m);
    }

    if (lane == 0) {
        *reinterpret_cast<float2*>(out + row0) = make_float2(s0 + bias0, s1 + bias1);
    }
}

extern "C" void kernel_launch(void* const* d_in, const int* in_sizes, int n_in,
                              void* d_out, int out_size, void* d_ws, size_t ws_size,
                              hipStream_t stream) {
    const int*   i1 = (const int*)d_in[0];
    const int*   i2 = (const int*)d_in[1];
    const float* W1 = (const float*)d_in[2];
    const float* W2 = (const float*)d_in[3];
    const float* b1 = (const float*)d_in[4];
    const float* b2 = (const float*)d_in[5];
    float* out = (float*)d_out;

    const int batch = in_sizes[0];                  // 16384
    const int block = 256;
    const int rows_per_block = (block / 32) * 2;    // 8 groups x 2 rows = 16
    const int grid = (batch + rows_per_block - 1) / rows_per_block;  // 1024

    fused_embed_dot_kernel<<<grid, block, 0, stream>>>(i1, i2, W1, W2, b1, b2, out, batch);
}